// Round 22
// baseline (105.041 us; speedup 1.0000x reference)
//
#include <hip/hip_runtime.h>
#include <hip/hip_bf16.h>
#include <stdint.h>

// Problem constants (fixed by the reference)
#define P 2048       // D_STATE
#define HN 64        // D_INPUT
#define L 16384      // kernel_size
#define BN 32        // l-columns per block
#define KSTEPS 128   // total K-steps (16 complex p each); 32 per wave (split-K)

typedef __bf16 bf16_t;
typedef bf16_t bf16x8 __attribute__((ext_vector_type(8)));
typedef float f32x16 __attribute__((ext_vector_type(16)));

__device__ __forceinline__ float2 cmul(float2 a, float2 b) {
    return make_float2(a.x * b.x - a.y * b.y, a.x * b.y + a.y * b.x);
}

__device__ __forceinline__ uint32_t packbf(float2 v) {
    union { __hip_bfloat162 v; uint32_t u; } cv;
    cv.v = __float22bfloat162_rn(make_float2(v.x, v.y));
    return cv.u;
}

// ---------------------------------------------------------------------------
// Prep (grid 128 x 256): three block-invariant tables in d_ws.
// (a) wexp: W in bf16 32x32-MFMA A-fragment order; granule gid =
//     kt*256 + q*128 + mt*64 + lane holds A[m=mt*32+(lane&31)] over p-run
//     kt*16 + q*8 + (lane>>5)*4 as (W_re, -W_im) bf16 pairs.
// (b) Tcol[p*32 + lc] = A_p^lc, lc in [0,32)   (float2, 512 KB).
// (c) TB[bn*2048 + p] = A_p^(32*bn), bn in [0,512)  (float2, 8 MB) — pure
//     multiplication ladders, no transcendentals.
__global__ void mv_prep(const float* __restrict__ Win,
                        const float* __restrict__ Ain,
                        uint4* __restrict__ wexp,
                        float2* __restrict__ tcol,
                        float2* __restrict__ tb) {
    int gid = blockIdx.x * 256 + threadIdx.x;   // 32768
    {   // (a) wexp
        int lane = gid & 63;
        int mt = (gid >> 6) & 1;
        int q = (gid >> 7) & 1;
        int kt = gid >> 8;
        int m = mt * 32 + (lane & 31);
        int p0 = kt * 16 + q * 8 + (lane >> 5) * 4;
        const float4* wp = (const float4*)(Win + (size_t)(m * P + p0) * 2);
        float4 f0 = wp[0], f1 = wp[1];
        float re[4] = {f0.x, f0.z, f1.x, f1.z};
        float im[4] = {f0.y, f0.w, f1.y, f1.w};
        uint32_t o[4];
#pragma unroll
        for (int j = 0; j < 4; ++j)
            o[j] = packbf(make_float2(re[j], -im[j]));
        wexp[gid] = make_uint4(o[0], o[1], o[2], o[3]);
    }
    {   // (b) Tcol: p = gid>>4, lc = 2*(gid&15), 2*(gid&15)+1
        int p = gid >> 4;
        int e = gid & 15;
        float2 a = *(const float2*)(Ain + 2 * p);
        float2 a2 = cmul(a, a);
        float2 r = make_float2(1.f, 0.f);
        float2 sq = a2;
#pragma unroll
        for (int b = 0; b < 4; ++b) {
            if ((e >> b) & 1) r = cmul(r, sq);
            sq = cmul(sq, sq);
        }
        tcol[(size_t)p * 32 + 2 * e] = r;
        tcol[(size_t)p * 32 + 2 * e + 1] = cmul(r, a);
    }
    {   // (c) TB: thread owns p = gid&2047, bn = bn0 + 16*i
        int p = gid & 2047;
        int bn0 = gid >> 11;                    // [0,16)
        float2 a = *(const float2*)(Ain + 2 * p);
        float2 a32 = a;
#pragma unroll
        for (int s = 0; s < 5; ++s) a32 = cmul(a32, a32);   // A^32
        float2 a512 = a32;
#pragma unroll
        for (int s = 0; s < 4; ++s) a512 = cmul(a512, a512); // A^512
        // r = (A^32)^bn0
        float2 r = make_float2(1.f, 0.f);
        float2 sq = a32;
#pragma unroll
        for (int b = 0; b < 4; ++b) {
            if ((bn0 >> b) & 1) r = cmul(r, sq);
            sq = cmul(sq, sq);
        }
#pragma unroll 4
        for (int i = 0; i < 32; ++i) {
            tb[(size_t)(bn0 + 16 * i) * P + p] = r;          // A^(32bn0+512i)
            r = cmul(r, a512);
        }
    }
}

// ---------------------------------------------------------------------------
// Main: grid 512 x 256 thr. Wave w: kt in [32w, 32w+32) (split-K), both
// 32-row m-tiles, 32x32x16 MFMA, B generated in-register (Base x Tcol).
// No barriers in the K-loop; compiler-pipelined loads (unroll 4).
__global__ void __launch_bounds__(256, 2) mv_main(
    const uint4* __restrict__ wexp,
    const float2* __restrict__ Tcol,
    const float2* __restrict__ TB,
    float* __restrict__ out) {
    __shared__ __align__(16) float2 Base[P];   // 16 KB: A_p^(32*bn)
    __shared__ float Red[4][2048];             // 32 KB: per-wave partials

    const int t = threadIdx.x;
    const int bn = blockIdx.x;
    const int w = t >> 6;
    const int lw = t & 63;

    {   // Base <- TB[bn] (16 KB coalesced)
        const float4* src = (const float4*)(TB + (size_t)bn * P);
        float4* dst = (float4*)Base;
#pragma unroll
        for (int j = 0; j < 4; ++j)
            dst[j * 256 + t] = src[j * 256 + t];
    }
    __syncthreads();

    const int n = lw & 31;         // column within tile
    const int kh = lw >> 5;        // k-half of the fragment

    f32x16 acc0, acc1;
#pragma unroll
    for (int r = 0; r < 16; ++r) { acc0[r] = 0.f; acc1[r] = 0.f; }

    const int kt0 = w * 32;
    const uint4* wq = wexp + (size_t)kt0 * 256 + lw;
    const float2* tq = Tcol + (size_t)kt0 * 512 + kh * 128 + n;
    const float4* bb = ((const float4*)Base) + kt0 * 8 + kh * 2;

#pragma unroll 4
    for (int kt = 0; kt < 32; ++kt) {
        // A-fragments (global, L2-resident; compile-time offsets)
        uint4 a00 = wq[0];     // mt0 q0
        uint4 a10 = wq[64];    // mt1 q0
        uint4 a01 = wq[128];   // mt0 q1
        uint4 a11 = wq[192];   // mt1 q1
#pragma unroll
        for (int q = 0; q < 2; ++q) {
            float2 t0 = tq[q * 256];
            float2 t1 = tq[q * 256 + 32];
            float2 t2 = tq[q * 256 + 64];
            float2 t3 = tq[q * 256 + 96];
            float4 bq0 = bb[q * 4];
            float4 bq1 = bb[q * 4 + 1];
            uint32_t f0 = packbf(cmul(make_float2(bq0.x, bq0.y), t0));
            uint32_t f1 = packbf(cmul(make_float2(bq0.z, bq0.w), t1));
            uint32_t f2 = packbf(cmul(make_float2(bq1.x, bq1.y), t2));
            uint32_t f3 = packbf(cmul(make_float2(bq1.z, bq1.w), t3));
            union { uint4 u; bf16x8 b; } bf, am0, am1;
            bf.u = make_uint4(f0, f1, f2, f3);
            am0.u = q ? a01 : a00;
            am1.u = q ? a11 : a10;
            acc0 = __builtin_amdgcn_mfma_f32_32x32x16_bf16(am0.b, bf.b, acc0, 0, 0, 0);
            acc1 = __builtin_amdgcn_mfma_f32_32x32x16_bf16(am1.b, bf.b, acc1, 0, 0, 0);
        }
        wq += 256; tq += 512; bb += 8;
    }

    // ---- cross-wave reduction (split-K) ----
#pragma unroll
    for (int r = 0; r < 16; ++r) {
        Red[w][r * 64 + lw] = acc0[r];
        Red[w][(16 + r) * 64 + lw] = acc1[r];
    }
    __syncthreads();

    // C/D layout (m74): col = lane&31, row = (r&3) + 8*(r>>2) + 4*(lane>>5)
#pragma unroll
    for (int i = 0; i < 8; ++i) {
        int idx = i * 256 + t;
        float s = Red[0][idx] + Red[1][idx] + Red[2][idx] + Red[3][idx];
        int lane = idx & 63;
        int r = (idx >> 6) & 15;
        int mt = idx >> 10;
        int row = (r & 3) + 8 * (r >> 2) + 4 * (lane >> 5);
        int hh = mt * 32 + row;
        int ll = bn * BN + (lane & 31);
        out[(size_t)hh * L + ll] = s;
    }
}

// ---------------------------------------------------------------------------
extern "C" void kernel_launch(void* const* d_in, const int* in_sizes, int n_in,
                              void* d_out, int out_size, void* d_ws, size_t ws_size,
                              hipStream_t stream) {
    const float* Ain = nullptr;
    const float* Win = nullptr;
    for (int i = 0; i < n_in; ++i) {
        if (in_sizes[i] == 2 * P) Ain = (const float*)d_in[i];
        else if (in_sizes[i] == 2 * HN * P) Win = (const float*)d_in[i];
    }
    if (!Ain) Ain = (const float*)d_in[0];
    if (!Win) Win = (const float*)d_in[1];
    (void)out_size; (void)ws_size;                          // ws >= 9 MB (256 MB measured R20)
    uint4* wexp = (uint4*)d_ws;                             // 512 KB
    float2* tcol = (float2*)((char*)d_ws + 512 * 1024);     // +512 KB
    float2* tb = (float2*)((char*)d_ws + 1024 * 1024);      // +8 MB
    mv_prep<<<128, 256, 0, stream>>>(Win, Ain, wexp, tcol, tb);
    mv_main<<<L / BN, 256, 0, stream>>>(wexp, tcol, tb, (float*)d_out);
}